// Round 1
// baseline (3185.503 us; speedup 1.0000x reference)
//
#include <hip/hip_runtime.h>
#include <math.h>

#define BB 32
#define LL 1024
#define EMB 512
#define DOUT 64
#define NH 8

// ---------------------------------------------------------------------------
// Kernel A: fused QKV projection.
// C[64x64] tile of X[32768,512] @ W[512,64] per (head, mat) + bias.
// grid.x = 512 row tiles, grid.y = 24 (= head*3 + mat)
// ---------------------------------------------------------------------------
__global__ __launch_bounds__(256) void qkv_kernel(
    const float* __restrict__ joint,
    const float* __restrict__ Wq, const float* __restrict__ Wk, const float* __restrict__ Wv,
    const float* __restrict__ bq, const float* __restrict__ bk, const float* __restrict__ bv,
    float* __restrict__ Qb, float* __restrict__ Kb, float* __restrict__ Vb)
{
    __shared__ __align__(16) float Xs[32][68];   // transposed: Xs[k][m]
    __shared__ __align__(16) float Ws[32][68];   // natural:    Ws[k][n]

    const int tid = threadIdx.x;
    const int tx = tid & 15, ty = tid >> 4;
    const int rowbase = blockIdx.x * 64;
    const int ym = blockIdx.y;
    const int mat = ym % 3;
    const int h = ym / 3;

    const float* W    = (mat == 0 ? Wq : (mat == 1 ? Wk : Wv)) + (size_t)h * EMB * DOUT;
    const float* bias = (mat == 0 ? bq : (mat == 1 ? bk : bv)) + (size_t)h * DOUT;
    float* Out        = (mat == 0 ? Qb : (mat == 1 ? Kb : Vb));

    float acc[4][4] = {};

    for (int kb = 0; kb < EMB; kb += 32) {
        __syncthreads();
        // X tile: 64 rows x 32 k -> transposed store
        #pragma unroll
        for (int p = 0; p < 2; ++p) {
            int f = tid + p * 256;        // 0..511
            int m = f >> 3;               // row 0..63
            int k4 = f & 7;               // float4 index in k (0..7)
            const float4 x = *reinterpret_cast<const float4*>(
                &joint[(size_t)(rowbase + m) * EMB + kb + k4 * 4]);
            Xs[k4 * 4 + 0][m] = x.x;
            Xs[k4 * 4 + 1][m] = x.y;
            Xs[k4 * 4 + 2][m] = x.z;
            Xs[k4 * 4 + 3][m] = x.w;
        }
        // W tile: 32 k x 64 n, natural
        #pragma unroll
        for (int p = 0; p < 2; ++p) {
            int f = tid + p * 256;        // 0..511
            int k = f >> 4;               // 0..31
            int c4 = f & 15;              // 0..15
            *reinterpret_cast<float4*>(&Ws[k][c4 * 4]) =
                *reinterpret_cast<const float4*>(&W[(size_t)(kb + k) * DOUT + c4 * 4]);
        }
        __syncthreads();

        #pragma unroll
        for (int k = 0; k < 32; ++k) {
            const float4 a = *reinterpret_cast<const float4*>(&Xs[k][ty * 4]);
            const float4 b = *reinterpret_cast<const float4*>(&Ws[k][tx * 4]);
            float av[4] = {a.x, a.y, a.z, a.w};
            float bv4[4] = {b.x, b.y, b.z, b.w};
            #pragma unroll
            for (int i = 0; i < 4; ++i)
                #pragma unroll
                for (int j = 0; j < 4; ++j)
                    acc[i][j] += av[i] * bv4[j];
        }
    }

    const float4 bz = *reinterpret_cast<const float4*>(&bias[tx * 4]);
    const float bzv[4] = {bz.x, bz.y, bz.z, bz.w};
    #pragma unroll
    for (int i = 0; i < 4; ++i) {
        int row = rowbase + ty * 4 + i;
        int b_ = row >> 10;
        int l = row & 1023;
        float4 o;
        o.x = acc[i][0] + bzv[0];
        o.y = acc[i][1] + bzv[1];
        o.z = acc[i][2] + bzv[2];
        o.w = acc[i][3] + bzv[3];
        *reinterpret_cast<float4*>(
            &Out[(((size_t)b_ * NH + h) * LL + l) * DOUT + tx * 4]) = o;
    }
}

// ---------------------------------------------------------------------------
// Kernel B: flash-style masked attention, faithful multiplicative mask.
// Block = (qtile of 32 rows, head, batch). 256 threads: ty=tid/16 owns rows
// 2*ty, 2*ty+1; tx owns strided cols {tx, tx+16, tx+32, tx+48}.
// Writes attention output IN PLACE over the Q buffer (each block only reads
// its own 32 Q rows, which no other block touches).
// ---------------------------------------------------------------------------
__global__ __launch_bounds__(256) void attn_kernel(
    float* Qb,                       // read Q, write O (aliased: no restrict)
    const float* __restrict__ Kb,
    const float* __restrict__ Vb,
    const int* __restrict__ traj_len)
{
    __shared__ __align__(16) float Qs[32][68];   // [row][d]
    __shared__ __align__(16) float Ks[64][68];   // [kcol][d]
    __shared__ __align__(16) float Vt[64][68];   // transposed: [col][k]
    __shared__ __align__(16) float Ps[32][68];   // [row][k]

    const int tid = threadIdx.x;
    const int tx = tid & 15, ty = tid >> 4;
    const int qt = blockIdx.x;
    const int h = blockIdx.y;
    const int b = blockIdx.z;

    int len = traj_len[b];
    if (len < 0) len = 0;
    if (len > LL) len = LL;

    const size_t base = ((size_t)b * NH + h) * LL * DOUT;
    const int qbase = qt * 32;

    // load Q tile (32 x 64)
    #pragma unroll
    for (int p = 0; p < 2; ++p) {
        int f = tid + p * 256;
        int m = f >> 4;
        int c4 = f & 15;
        *reinterpret_cast<float4*>(&Qs[m][c4 * 4]) =
            *reinterpret_cast<const float4*>(&Qb[base + (size_t)(qbase + m) * DOUT + c4 * 4]);
    }

    const int r0 = ty * 2, r1 = r0 + 1;
    const bool q0v = (qbase + r0) < len;
    const bool q1v = (qbase + r1) < len;
    const float scale = 0.044194173824159216f;   // 1/sqrt(512)

    float m0 = -1e30f, m1 = -1e30f;
    float l0 = 0.f, l1 = 0.f;
    float o0[4] = {}, o1[4] = {};

    for (int kt = 0; kt < LL; kt += 64) {
        __syncthreads();   // previous iteration's Ks/Vt readers are done
        // K tile natural, V tile transposed
        #pragma unroll
        for (int p = 0; p < 4; ++p) {
            int f = tid + p * 256;        // 0..1023
            int m = f >> 4;               // 0..63
            int c4 = f & 15;
            *reinterpret_cast<float4*>(&Ks[m][c4 * 4]) =
                *reinterpret_cast<const float4*>(&Kb[base + (size_t)(kt + m) * DOUT + c4 * 4]);
            const float4 v = *reinterpret_cast<const float4*>(
                &Vb[base + (size_t)(kt + m) * DOUT + c4 * 4]);
            Vt[c4 * 4 + 0][m] = v.x;
            Vt[c4 * 4 + 1][m] = v.y;
            Vt[c4 * 4 + 2][m] = v.z;
            Vt[c4 * 4 + 3][m] = v.w;
        }
        __syncthreads();

        // S = Q K^T for 2 rows x 4 strided cols
        float s0[4] = {}, s1[4] = {};
        #pragma unroll
        for (int d4 = 0; d4 < 16; ++d4) {
            const float4 a0 = *reinterpret_cast<const float4*>(&Qs[r0][d4 * 4]);
            const float4 a1 = *reinterpret_cast<const float4*>(&Qs[r1][d4 * 4]);
            #pragma unroll
            for (int j = 0; j < 4; ++j) {
                const float4 kk = *reinterpret_cast<const float4*>(&Ks[tx + 16 * j][d4 * 4]);
                s0[j] += a0.x * kk.x + a0.y * kk.y + a0.z * kk.z + a0.w * kk.w;
                s1[j] += a1.x * kk.x + a1.y * kk.y + a1.z * kk.z + a1.w * kk.w;
            }
        }

        // multiplicative mask (masked logits become 0, still in softmax)
        #pragma unroll
        for (int j = 0; j < 4; ++j) {
            const bool kv = (kt + tx + 16 * j) < len;
            s0[j] = (q0v && kv) ? s0[j] * scale : 0.0f;
            s1[j] = (q1v && kv) ? s1[j] * scale : 0.0f;
        }

        // row max across 16 lanes (same ty = contiguous 16 lanes of a wave)
        float mt0 = fmaxf(fmaxf(s0[0], s0[1]), fmaxf(s0[2], s0[3]));
        float mt1 = fmaxf(fmaxf(s1[0], s1[1]), fmaxf(s1[2], s1[3]));
        #pragma unroll
        for (int off = 1; off < 16; off <<= 1) {
            mt0 = fmaxf(mt0, __shfl_xor(mt0, off, 64));
            mt1 = fmaxf(mt1, __shfl_xor(mt1, off, 64));
        }
        const float mn0 = fmaxf(m0, mt0);
        const float mn1 = fmaxf(m1, mt1);
        const float al0 = __expf(m0 - mn0);
        const float al1 = __expf(m1 - mn1);

        float p0[4], p1[4];
        float rs0 = 0.f, rs1 = 0.f;
        #pragma unroll
        for (int j = 0; j < 4; ++j) {
            p0[j] = __expf(s0[j] - mn0);
            p1[j] = __expf(s1[j] - mn1);
            rs0 += p0[j];
            rs1 += p1[j];
        }
        #pragma unroll
        for (int off = 1; off < 16; off <<= 1) {
            rs0 += __shfl_xor(rs0, off, 64);
            rs1 += __shfl_xor(rs1, off, 64);
        }
        l0 = l0 * al0 + rs0;
        l1 = l1 * al1 + rs1;
        m0 = mn0;
        m1 = mn1;
        #pragma unroll
        for (int j = 0; j < 4; ++j) { o0[j] *= al0; o1[j] *= al1; }

        // publish P
        #pragma unroll
        for (int j = 0; j < 4; ++j) {
            Ps[r0][tx + 16 * j] = p0[j];
            Ps[r1][tx + 16 * j] = p1[j];
        }
        __syncthreads();

        // O += P V  (Vt rows are V columns)
        #pragma unroll
        for (int k4 = 0; k4 < 16; ++k4) {
            const float4 pp0 = *reinterpret_cast<const float4*>(&Ps[r0][k4 * 4]);
            const float4 pp1 = *reinterpret_cast<const float4*>(&Ps[r1][k4 * 4]);
            #pragma unroll
            for (int j = 0; j < 4; ++j) {
                const float4 vv = *reinterpret_cast<const float4*>(&Vt[tx + 16 * j][k4 * 4]);
                o0[j] += pp0.x * vv.x + pp0.y * vv.y + pp0.z * vv.z + pp0.w * vv.w;
                o1[j] += pp1.x * vv.x + pp1.y * vv.y + pp1.z * vv.z + pp1.w * vv.w;
            }
        }
    }

    const float inv0 = 1.0f / l0;
    const float inv1 = 1.0f / l1;
    #pragma unroll
    for (int j = 0; j < 4; ++j) {
        Qb[base + (size_t)(qbase + r0) * DOUT + tx + 16 * j] = o0[j] * inv0;
        Qb[base + (size_t)(qbase + r1) * DOUT + tx + 16 * j] = o1[j] * inv1;
    }
}

// ---------------------------------------------------------------------------
// Kernel C: output projection. out[32768,64] = concat[32768,512] @ Wo[512,64]
// where concat[row, h*64+j] = attnout[b,h,l,j] (attnout lives in the Q buffer).
// One 64-row tile per block; K chunks of 64 = one head each.
// ---------------------------------------------------------------------------
__global__ __launch_bounds__(256) void outproj_kernel(
    const float* __restrict__ Ab,    // attnout [B,NH,L,64]
    const float* __restrict__ Wo,    // [512,64]
    float* __restrict__ out)         // [B*L,64]
{
    __shared__ __align__(16) float As[64][68];   // transposed: As[k][m]
    __shared__ __align__(16) float Ws[64][68];   // natural

    const int tid = threadIdx.x;
    const int tx = tid & 15, ty = tid >> 4;
    const int rowbase = blockIdx.x * 64;
    const int b = rowbase >> 10;
    const int lbase = rowbase & 1023;

    float acc[4][4] = {};

    for (int h = 0; h < NH; ++h) {
        __syncthreads();
        #pragma unroll
        for (int p = 0; p < 4; ++p) {
            int f = tid + p * 256;        // 0..1023
            int m = f >> 4;               // 0..63
            int c4 = f & 15;
            const float4 a = *reinterpret_cast<const float4*>(
                &Ab[(((size_t)b * NH + h) * LL + lbase + m) * DOUT + c4 * 4]);
            As[c4 * 4 + 0][m] = a.x;
            As[c4 * 4 + 1][m] = a.y;
            As[c4 * 4 + 2][m] = a.z;
            As[c4 * 4 + 3][m] = a.w;
            *reinterpret_cast<float4*>(&Ws[m][c4 * 4]) =
                *reinterpret_cast<const float4*>(&Wo[(size_t)(h * 64 + m) * DOUT + c4 * 4]);
        }
        __syncthreads();

        #pragma unroll
        for (int k = 0; k < 64; ++k) {
            const float4 a = *reinterpret_cast<const float4*>(&As[k][ty * 4]);
            const float4 w = *reinterpret_cast<const float4*>(&Ws[k][tx * 4]);
            float av[4] = {a.x, a.y, a.z, a.w};
            float wv[4] = {w.x, w.y, w.z, w.w};
            #pragma unroll
            for (int i = 0; i < 4; ++i)
                #pragma unroll
                for (int j = 0; j < 4; ++j)
                    acc[i][j] += av[i] * wv[j];
        }
    }

    #pragma unroll
    for (int i = 0; i < 4; ++i) {
        float4 o;
        o.x = acc[i][0]; o.y = acc[i][1]; o.z = acc[i][2]; o.w = acc[i][3];
        *reinterpret_cast<float4*>(
            &out[(size_t)(rowbase + ty * 4 + i) * DOUT + tx * 4]) = o;
    }
}

// ---------------------------------------------------------------------------
extern "C" void kernel_launch(void* const* d_in, const int* in_sizes, int n_in,
                              void* d_out, int out_size, void* d_ws, size_t ws_size,
                              hipStream_t stream) {
    const float* joint = (const float*)d_in[0];
    // d_in[1] = delta: only defines the mask shape in the reference; never read.
    const int* traj = (const int*)d_in[2];
    const float* Wq = (const float*)d_in[3];
    const float* Wk = (const float*)d_in[4];
    const float* Wv = (const float*)d_in[5];
    const float* bq = (const float*)d_in[6];
    const float* bk = (const float*)d_in[7];
    const float* bv = (const float*)d_in[8];
    const float* Wo = (const float*)d_in[9];
    float* out = (float*)d_out;

    const size_t NQ = (size_t)BB * NH * LL * DOUT;   // 16,777,216 floats
    float* Qb = (float*)d_ws;
    float* Kb = Qb + NQ;
    float* Vb = Kb + NQ;

    qkv_kernel<<<dim3(512, 24), 256, 0, stream>>>(joint, Wq, Wk, Wv, bq, bk, bv,
                                                  Qb, Kb, Vb);
    attn_kernel<<<dim3(32, NH, BB), 256, 0, stream>>>(Qb, Kb, Vb, traj);
    outproj_kernel<<<dim3(512), 256, 0, stream>>>(Qb, Wo, out);
}

// Round 2
// 1190.055 us; speedup vs baseline: 2.6768x; 2.6768x over previous
//
#include <hip/hip_runtime.h>
#include <math.h>

#define BB 32
#define LL 1024
#define EMB 512
#define DOUT 64
#define NH 8

typedef __attribute__((ext_vector_type(8))) short short8;
typedef __attribute__((ext_vector_type(4))) float f32x4;

union S8 { short8 v; unsigned u[4]; };

// pack 2 floats -> 2 bf16 (RNE), low = a, high = b
__device__ __forceinline__ unsigned pk2(float a, float b) {
    unsigned ua = __float_as_uint(a);
    ua += 0x7fffu + ((ua >> 16) & 1u);
    unsigned ub = __float_as_uint(b);
    ub += 0x7fffu + ((ub >> 16) & 1u);
    return (ua >> 16) | (ub & 0xffff0000u);
}

// ---------------------------------------------------------------------------
// Kernel A: fused QKV projection (fp32, unchanged from round 1).
// ---------------------------------------------------------------------------
__global__ __launch_bounds__(256) void qkv_kernel(
    const float* __restrict__ joint,
    const float* __restrict__ Wq, const float* __restrict__ Wk, const float* __restrict__ Wv,
    const float* __restrict__ bq, const float* __restrict__ bk, const float* __restrict__ bv,
    float* __restrict__ Qb, float* __restrict__ Kb, float* __restrict__ Vb)
{
    __shared__ __align__(16) float Xs[32][68];   // transposed: Xs[k][m]
    __shared__ __align__(16) float Ws[32][68];   // natural:    Ws[k][n]

    const int tid = threadIdx.x;
    const int tx = tid & 15, ty = tid >> 4;
    const int rowbase = blockIdx.x * 64;
    const int ym = blockIdx.y;
    const int mat = ym % 3;
    const int h = ym / 3;

    const float* W    = (mat == 0 ? Wq : (mat == 1 ? Wk : Wv)) + (size_t)h * EMB * DOUT;
    const float* bias = (mat == 0 ? bq : (mat == 1 ? bk : bv)) + (size_t)h * DOUT;
    float* Out        = (mat == 0 ? Qb : (mat == 1 ? Kb : Vb));

    float acc[4][4] = {};

    for (int kb = 0; kb < EMB; kb += 32) {
        __syncthreads();
        #pragma unroll
        for (int p = 0; p < 2; ++p) {
            int f = tid + p * 256;
            int m = f >> 3;
            int k4 = f & 7;
            const float4 x = *reinterpret_cast<const float4*>(
                &joint[(size_t)(rowbase + m) * EMB + kb + k4 * 4]);
            Xs[k4 * 4 + 0][m] = x.x;
            Xs[k4 * 4 + 1][m] = x.y;
            Xs[k4 * 4 + 2][m] = x.z;
            Xs[k4 * 4 + 3][m] = x.w;
        }
        #pragma unroll
        for (int p = 0; p < 2; ++p) {
            int f = tid + p * 256;
            int k = f >> 4;
            int c4 = f & 15;
            *reinterpret_cast<float4*>(&Ws[k][c4 * 4]) =
                *reinterpret_cast<const float4*>(&W[(size_t)(kb + k) * DOUT + c4 * 4]);
        }
        __syncthreads();

        #pragma unroll
        for (int k = 0; k < 32; ++k) {
            const float4 a = *reinterpret_cast<const float4*>(&Xs[k][ty * 4]);
            const float4 b = *reinterpret_cast<const float4*>(&Ws[k][tx * 4]);
            float av[4] = {a.x, a.y, a.z, a.w};
            float bv4[4] = {b.x, b.y, b.z, b.w};
            #pragma unroll
            for (int i = 0; i < 4; ++i)
                #pragma unroll
                for (int j = 0; j < 4; ++j)
                    acc[i][j] += av[i] * bv4[j];
        }
    }

    const float4 bz = *reinterpret_cast<const float4*>(&bias[tx * 4]);
    const float bzv[4] = {bz.x, bz.y, bz.z, bz.w};
    #pragma unroll
    for (int i = 0; i < 4; ++i) {
        int row = rowbase + ty * 4 + i;
        int b_ = row >> 10;
        int l = row & 1023;
        float4 o;
        o.x = acc[i][0] + bzv[0];
        o.y = acc[i][1] + bzv[1];
        o.z = acc[i][2] + bzv[2];
        o.w = acc[i][3] + bzv[3];
        *reinterpret_cast<float4*>(
            &Out[(((size_t)b_ * NH + h) * LL + l) * DOUT + tx * 4]) = o;
    }
}

// ---------------------------------------------------------------------------
// Kernel B: bf16-MFMA flash attention, multiplicative mask, max-free softmax.
// Block = 256 thr (4 waves), 128 q-rows; wave owns 32 rows (2 groups of 16).
// S^T = K.Q^T via mfma_f32_16x16x32_bf16 (lane's scores all share one q col),
// P -> per-wave LDS (A-layout) -> O += P.V. K/Vt/Ps use XOR-swizzled 16B
// blocks (row stride 128B, conflict-free b128 frag reads).
// Writes O in place over Qb (block-private rows).
// ---------------------------------------------------------------------------
__global__ __launch_bounds__(256, 3) void attn_kernel(
    float* Qb,
    const float* __restrict__ Kb,
    const float* __restrict__ Vb,
    const int* __restrict__ traj_len)
{
    __shared__ __align__(16) short lds[16384];   // 32 KB
    short* Ks = lds;              // [64 keys][64 d] bf16, swizzled
    short* Vt = lds + 4096;       // [64 d][64 keys] bf16, swizzled

    const int tid = threadIdx.x;
    const int lane = tid & 63;
    const int wid = tid >> 6;
    const int lq = lane & 15;
    const int quad = lane >> 4;
    short* Ps = lds + 8192 + wid * 2048;   // per-wave [32 q][64 k] bf16, swizzled

    const int qt = blockIdx.x;
    const int h = blockIdx.y;
    const int b = blockIdx.z;

    int len = traj_len[b];
    if (len < 0) len = 0;
    if (len > LL) len = LL;

    const size_t base = ((size_t)b * NH + h) * LL * DOUT;
    const int qbase = qt * 128 + wid * 32;

    // Q fragments: row = qbase+16g+lq, d = kf*32 + quad*8 .. +7 (A/B-frag load)
    short8 qf[2][2];
    #pragma unroll
    for (int g = 0; g < 2; ++g) {
        #pragma unroll
        for (int kf = 0; kf < 2; ++kf) {
            const float* s = &Qb[base + (size_t)(qbase + 16 * g + lq) * DOUT + kf * 32 + quad * 8];
            const float4 x0 = *reinterpret_cast<const float4*>(s);
            const float4 x1 = *reinterpret_cast<const float4*>(s + 4);
            S8 t;
            t.u[0] = pk2(x0.x, x0.y);
            t.u[1] = pk2(x0.z, x0.w);
            t.u[2] = pk2(x1.x, x1.y);
            t.u[3] = pk2(x1.z, x1.w);
            qf[g][kf] = t.v;
        }
    }

    const float SC = 0.04419417382415922f;   // 1/sqrt(512)
    float Mq[2];
    Mq[0] = ((qbase + lq) < len) ? SC : 0.0f;
    Mq[1] = ((qbase + 16 + lq) < len) ? SC : 0.0f;
    const int krel = len - 4 * quad;         // k valid iff kt+16nt+r < krel

    f32x4 o[2][4];
    #pragma unroll
    for (int g = 0; g < 2; ++g)
        #pragma unroll
        for (int nt = 0; nt < 4; ++nt) {
            o[g][nt][0] = 0.f; o[g][nt][1] = 0.f; o[g][nt][2] = 0.f; o[g][nt][3] = 0.f;
        }
    float l_acc[2] = {0.0f, 0.0f};

    for (int kt = 0; kt < LL; kt += 64) {
        __syncthreads();
        // ---- stage K tile (64 keys x 64 d) as bf16, swizzled 16B blocks ----
        #pragma unroll
        for (int p = 0; p < 2; ++p) {
            const int bidx = tid + p * 256;
            const int m = bidx >> 3;
            const int j = bidx & 7;
            const float* s = &Kb[base + (size_t)(kt + m) * DOUT + 8 * j];
            const float4 a = *reinterpret_cast<const float4*>(s);
            const float4 c = *reinterpret_cast<const float4*>(s + 4);
            S8 t;
            t.u[0] = pk2(a.x, a.y);
            t.u[1] = pk2(a.z, a.w);
            t.u[2] = pk2(c.x, c.y);
            t.u[3] = pk2(c.z, c.w);
            *reinterpret_cast<short8*>(&Ks[m * 64 + 8 * (j ^ (m & 7))]) = t.v;
        }
        // ---- stage V tile transposed: Vt[d][k] = V[kt+k][d] ----
        {
            const int d = tid & 63;
            const int j0 = tid >> 6;
            #pragma unroll
            for (int p = 0; p < 2; ++p) {
                const int j = j0 + 4 * p;
                const float* s = &Vb[base + (size_t)(kt + 8 * j) * DOUT + d];
                float v0 = s[0 * DOUT], v1 = s[1 * DOUT], v2 = s[2 * DOUT], v3 = s[3 * DOUT];
                float v4 = s[4 * DOUT], v5 = s[5 * DOUT], v6 = s[6 * DOUT], v7 = s[7 * DOUT];
                S8 t;
                t.u[0] = pk2(v0, v1);
                t.u[1] = pk2(v2, v3);
                t.u[2] = pk2(v4, v5);
                t.u[3] = pk2(v6, v7);
                *reinterpret_cast<short8*>(&Vt[d * 64 + 8 * (j ^ (d & 7))]) = t.v;
            }
        }
        __syncthreads();

        // ---- S^T = K . Q^T : 16x16 tiles, nt = key subtile, g = q group ----
        f32x4 sS[2][4];
        #pragma unroll
        for (int nt = 0; nt < 4; ++nt) {
            const int krow = (16 * nt + lq) * 64;
            const short8 k0 = *reinterpret_cast<const short8*>(&Ks[krow + 8 * ((0 + quad) ^ (lq & 7))]);
            const short8 k1 = *reinterpret_cast<const short8*>(&Ks[krow + 8 * ((4 + quad) ^ (lq & 7))]);
            #pragma unroll
            for (int g = 0; g < 2; ++g) {
                f32x4 z;
                z[0] = 0.f; z[1] = 0.f; z[2] = 0.f; z[3] = 0.f;
                z = __builtin_amdgcn_mfma_f32_16x16x32_bf16(k0, qf[g][0], z, 0, 0, 0);
                z = __builtin_amdgcn_mfma_f32_16x16x32_bf16(k1, qf[g][1], z, 0, 0, 0);
                sS[g][nt] = z;
            }
        }

        // ---- p = exp(s * scale * mask); accumulate l; write P (bf16) ----
        #pragma unroll
        for (int g = 0; g < 2; ++g) {
            #pragma unroll
            for (int nt = 0; nt < 4; ++nt) {
                float pv[4];
                #pragma unroll
                for (int r = 0; r < 4; ++r) {
                    const float mult = ((kt + 16 * nt + r) < krel) ? Mq[g] : 0.0f;
                    pv[r] = __expf(sS[g][nt][r] * mult);
                    l_acc[g] += pv[r];
                }
                int2 w;
                w.x = (int)pk2(pv[0], pv[1]);
                w.y = (int)pk2(pv[2], pv[3]);
                *reinterpret_cast<int2*>(
                    &Ps[(16 * g + lq) * 64 + 8 * ((2 * nt + (quad >> 1)) ^ (lq & 7)) + 4 * (quad & 1)]) = w;
            }
        }

        // ---- O += P . V ----
        short8 pf[2][2];
        #pragma unroll
        for (int g = 0; g < 2; ++g)
            #pragma unroll
            for (int kf = 0; kf < 2; ++kf)
                pf[g][kf] = *reinterpret_cast<const short8*>(
                    &Ps[(16 * g + lq) * 64 + 8 * ((4 * kf + quad) ^ (lq & 7))]);

        #pragma unroll
        for (int nt = 0; nt < 4; ++nt) {
            const int vrow = (16 * nt + lq) * 64;
            const short8 v0 = *reinterpret_cast<const short8*>(&Vt[vrow + 8 * ((0 + quad) ^ (lq & 7))]);
            const short8 v1 = *reinterpret_cast<const short8*>(&Vt[vrow + 8 * ((4 + quad) ^ (lq & 7))]);
            #pragma unroll
            for (int g = 0; g < 2; ++g) {
                o[g][nt] = __builtin_amdgcn_mfma_f32_16x16x32_bf16(pf[g][0], v0, o[g][nt], 0, 0, 0);
                o[g][nt] = __builtin_amdgcn_mfma_f32_16x16x32_bf16(pf[g][1], v1, o[g][nt], 0, 0, 0);
            }
        }
    }

    // ---- epilogue: reduce l across quads, redistribute 1/l, store O ----
    float inv[2];
    #pragma unroll
    for (int g = 0; g < 2; ++g) {
        float t = l_acc[g];
        t += __shfl_xor(t, 16);
        t += __shfl_xor(t, 32);
        inv[g] = 1.0f / t;
    }
    float iq[2][4];
    #pragma unroll
    for (int g = 0; g < 2; ++g)
        #pragma unroll
        for (int r = 0; r < 4; ++r)
            iq[g][r] = __shfl(inv[g], 4 * quad + r, 64);

    #pragma unroll
    for (int g = 0; g < 2; ++g) {
        #pragma unroll
        for (int nt = 0; nt < 4; ++nt) {
            #pragma unroll
            for (int r = 0; r < 4; ++r) {
                const int qrow = qbase + 16 * g + 4 * quad + r;
                Qb[base + (size_t)qrow * DOUT + 16 * nt + lq] = o[g][nt][r] * iq[g][r];
            }
        }
    }
}

// ---------------------------------------------------------------------------
// Kernel C: output projection (fp32, unchanged from round 1).
// ---------------------------------------------------------------------------
__global__ __launch_bounds__(256) void outproj_kernel(
    const float* __restrict__ Ab,
    const float* __restrict__ Wo,
    float* __restrict__ out)
{
    __shared__ __align__(16) float As[64][68];
    __shared__ __align__(16) float Ws[64][68];

    const int tid = threadIdx.x;
    const int tx = tid & 15, ty = tid >> 4;
    const int rowbase = blockIdx.x * 64;
    const int b = rowbase >> 10;
    const int lbase = rowbase & 1023;

    float acc[4][4] = {};

    for (int h = 0; h < NH; ++h) {
        __syncthreads();
        #pragma unroll
        for (int p = 0; p < 4; ++p) {
            int f = tid + p * 256;
            int m = f >> 4;
            int c4 = f & 15;
            const float4 a = *reinterpret_cast<const float4*>(
                &Ab[(((size_t)b * NH + h) * LL + lbase + m) * DOUT + c4 * 4]);
            As[c4 * 4 + 0][m] = a.x;
            As[c4 * 4 + 1][m] = a.y;
            As[c4 * 4 + 2][m] = a.z;
            As[c4 * 4 + 3][m] = a.w;
            *reinterpret_cast<float4*>(&Ws[m][c4 * 4]) =
                *reinterpret_cast<const float4*>(&Wo[(size_t)(h * 64 + m) * DOUT + c4 * 4]);
        }
        __syncthreads();

        #pragma unroll
        for (int k = 0; k < 64; ++k) {
            const float4 a = *reinterpret_cast<const float4*>(&As[k][ty * 4]);
            const float4 w = *reinterpret_cast<const float4*>(&Ws[k][tx * 4]);
            float av[4] = {a.x, a.y, a.z, a.w};
            float wv[4] = {w.x, w.y, w.z, w.w};
            #pragma unroll
            for (int i = 0; i < 4; ++i)
                #pragma unroll
                for (int j = 0; j < 4; ++j)
                    acc[i][j] += av[i] * wv[j];
        }
    }

    #pragma unroll
    for (int i = 0; i < 4; ++i) {
        float4 o;
        o.x = acc[i][0]; o.y = acc[i][1]; o.z = acc[i][2]; o.w = acc[i][3];
        *reinterpret_cast<float4*>(
            &out[(size_t)(rowbase + ty * 4 + i) * DOUT + tx * 4]) = o;
    }
}

// ---------------------------------------------------------------------------
extern "C" void kernel_launch(void* const* d_in, const int* in_sizes, int n_in,
                              void* d_out, int out_size, void* d_ws, size_t ws_size,
                              hipStream_t stream) {
    const float* joint = (const float*)d_in[0];
    // d_in[1] = delta: dead input (only defines mask shape); never read.
    const int* traj = (const int*)d_in[2];
    const float* Wq = (const float*)d_in[3];
    const float* Wk = (const float*)d_in[4];
    const float* Wv = (const float*)d_in[5];
    const float* bq = (const float*)d_in[6];
    const float* bk = (const float*)d_in[7];
    const float* bv = (const float*)d_in[8];
    const float* Wo = (const float*)d_in[9];
    float* out = (float*)d_out;

    const size_t NQ = (size_t)BB * NH * LL * DOUT;
    float* Qb = (float*)d_ws;
    float* Kb = Qb + NQ;
    float* Vb = Kb + NQ;

    qkv_kernel<<<dim3(512, 24), 256, 0, stream>>>(joint, Wq, Wk, Wv, bq, bk, bv,
                                                  Qb, Kb, Vb);
    attn_kernel<<<dim3(8, NH, BB), 256, 0, stream>>>(Qb, Kb, Vb, traj);
    outproj_kernel<<<dim3(512), 256, 0, stream>>>(Qb, Wo, out);
}

// Round 3
// 560.627 us; speedup vs baseline: 5.6820x; 2.1227x over previous
//
#include <hip/hip_runtime.h>
#include <math.h>

#define BB 32
#define LL 1024
#define EMB 512
#define DOUT 64
#define NH 8

typedef __attribute__((ext_vector_type(8))) short short8;
typedef __attribute__((ext_vector_type(4))) short short4v;
typedef __attribute__((ext_vector_type(8))) _Float16 half8;
typedef __attribute__((ext_vector_type(4))) float f32x4;

union S8 { short8 v; unsigned u[4]; };

// pack 2 floats -> 2 bf16 (RNE)
__device__ __forceinline__ unsigned pk2(float a, float b) {
    unsigned ua = __float_as_uint(a);
    ua += 0x7fffu + ((ua >> 16) & 1u);
    unsigned ub = __float_as_uint(b);
    ub += 0x7fffu + ((ub >> 16) & 1u);
    return (ua >> 16) | (ub & 0xffff0000u);
}
// pack 1 float -> bf16 (RNE)
__device__ __forceinline__ unsigned short pk1(float a) {
    unsigned ua = __float_as_uint(a);
    ua += 0x7fffu + ((ua >> 16) & 1u);
    return (unsigned short)(ua >> 16);
}
__device__ __forceinline__ float bf2f(unsigned short u) {
    return __uint_as_float(((unsigned)u) << 16);
}

// ---------------------------------------------------------------------------
// Kernel 0: convert. joint -> fp16 Xh; Wq/Wk/Wv -> fp16 transposed Wth[y][n][k]
// (y = h*3+mat); Wo -> bf16 transposed Wotb[n][k].
// ---------------------------------------------------------------------------
__global__ __launch_bounds__(256) void convert_kernel(
    const float* __restrict__ joint,
    const float* __restrict__ Wq, const float* __restrict__ Wk, const float* __restrict__ Wv,
    const float* __restrict__ Wo,
    _Float16* __restrict__ Xh, _Float16* __restrict__ Wth,
    unsigned short* __restrict__ Wotb)
{
    const int blk = blockIdx.x;
    const int tid = threadIdx.x;
    if (blk < 8192) {
        const size_t idx = ((size_t)blk * 256 + tid) * 8;
        const float4 a = *reinterpret_cast<const float4*>(&joint[idx]);
        const float4 b = *reinterpret_cast<const float4*>(&joint[idx + 4]);
        half8 h;
        h[0] = (_Float16)a.x; h[1] = (_Float16)a.y; h[2] = (_Float16)a.z; h[3] = (_Float16)a.w;
        h[4] = (_Float16)b.x; h[5] = (_Float16)b.y; h[6] = (_Float16)b.z; h[7] = (_Float16)b.w;
        *reinterpret_cast<half8*>(&Xh[idx]) = h;
    } else if (blk < 8192 + 384) {
        const int gid = (blk - 8192) * 256 + tid;   // [0, 98304)
        const int y = gid >> 12;                    // [0, 24)
        const int rem = gid & 4095;
        const int n = rem >> 6;
        const int k8 = rem & 63;
        const int h = y / 3, mat = y - 3 * h;
        const float* W = (mat == 0 ? Wq : (mat == 1 ? Wk : Wv)) + (size_t)h * EMB * DOUT;
        half8 t;
        #pragma unroll
        for (int i = 0; i < 8; ++i)
            t[i] = (_Float16)W[(size_t)(k8 * 8 + i) * DOUT + n];
        *reinterpret_cast<half8*>(&Wth[(size_t)y * 32768 + n * 512 + k8 * 8]) = t;
    } else {
        const int gid = (blk - 8576) * 256 + tid;   // [0, 4096)
        const int n = gid >> 6;
        const int k8 = gid & 63;
        short4v lo, hi;
        #pragma unroll
        for (int i = 0; i < 4; ++i) lo[i] = (short)pk1(Wo[(size_t)(k8 * 8 + i) * DOUT + n]);
        #pragma unroll
        for (int i = 0; i < 4; ++i) hi[i] = (short)pk1(Wo[(size_t)(k8 * 8 + 4 + i) * DOUT + n]);
        *reinterpret_cast<short4v*>(&Wotb[(size_t)n * 512 + k8 * 8]) = lo;
        *reinterpret_cast<short4v*>(&Wotb[(size_t)n * 512 + k8 * 8 + 4]) = hi;
    }
}

// ---------------------------------------------------------------------------
// Kernel 1: QKV projection with fp16 MFMA.
// Block: 256 thr (4 waves), tile 128 rows x 64 cols, K=512 in chunks of 64.
// grid (256 rowtiles, 24 = h*3+mat). LDS tiles XOR-swizzled (16B blocks).
// mfma(a,b): D[row=quad*4+r <- a's row idx][col=lane&15 <- b's row idx].
// Q/K: swapped operands -> d consecutive per lane -> natural [l][d] b64 stores.
// V: normal operands -> l consecutive per lane -> transposed [d][L] b64 stores.
// ---------------------------------------------------------------------------
template <bool VMODE>
__device__ __forceinline__ void qkv_core(
    const _Float16* __restrict__ Xh, const _Float16* __restrict__ Wy,
    _Float16* As, _Float16* Bs, f32x4 (&acc)[8], int rowbase)
{
    const int tid = threadIdx.x;
    const int lane = tid & 63;
    const int wid = tid >> 6;
    const int lq = lane & 15;
    const int quad = lane >> 4;

    for (int kb = 0; kb < EMB; kb += 64) {
        __syncthreads();
        #pragma unroll
        for (int p = 0; p < 4; ++p) {
            const int bidx = tid + p * 256;
            const int m = bidx >> 3, j = bidx & 7;
            const half8 t = *reinterpret_cast<const half8*>(
                &Xh[(size_t)(rowbase + m) * EMB + kb + 8 * j]);
            *reinterpret_cast<half8*>(&As[m * 64 + 8 * (j ^ (m & 7))]) = t;
        }
        #pragma unroll
        for (int p = 0; p < 2; ++p) {
            const int bidx = tid + p * 256;
            const int n = bidx >> 3, j = bidx & 7;
            const half8 t = *reinterpret_cast<const half8*>(
                &Wy[(size_t)n * EMB + kb + 8 * j]);
            *reinterpret_cast<half8*>(&Bs[n * 64 + 8 * (j ^ (n & 7))]) = t;
        }
        __syncthreads();

        half8 xf[2][2], wf[4][2];
        #pragma unroll
        for (int mt = 0; mt < 2; ++mt)
            #pragma unroll
            for (int kf = 0; kf < 2; ++kf) {
                const int row = wid * 32 + mt * 16 + lq;
                xf[mt][kf] = *reinterpret_cast<const half8*>(
                    &As[row * 64 + 8 * ((4 * kf + quad) ^ (row & 7))]);
            }
        #pragma unroll
        for (int nt = 0; nt < 4; ++nt)
            #pragma unroll
            for (int kf = 0; kf < 2; ++kf)
                wf[nt][kf] = *reinterpret_cast<const half8*>(
                    &Bs[(nt * 16 + lq) * 64 + 8 * ((4 * kf + quad) ^ (lq & 7))]);

        #pragma unroll
        for (int mt = 0; mt < 2; ++mt)
            #pragma unroll
            for (int nt = 0; nt < 4; ++nt)
                #pragma unroll
                for (int kf = 0; kf < 2; ++kf) {
                    if (VMODE)
                        acc[mt * 4 + nt] = __builtin_amdgcn_mfma_f32_16x16x32_f16(
                            xf[mt][kf], wf[nt][kf], acc[mt * 4 + nt], 0, 0, 0);
                    else
                        acc[mt * 4 + nt] = __builtin_amdgcn_mfma_f32_16x16x32_f16(
                            wf[nt][kf], xf[mt][kf], acc[mt * 4 + nt], 0, 0, 0);
                }
    }
}

__global__ __launch_bounds__(256) void qkv_mfma(
    const _Float16* __restrict__ Xh, const _Float16* __restrict__ Wth,
    const float* __restrict__ bq, const float* __restrict__ bk, const float* __restrict__ bv,
    unsigned short* __restrict__ Qb, unsigned short* __restrict__ Kb,
    unsigned short* __restrict__ Vb)
{
    __shared__ __align__(16) _Float16 As[128 * 64];
    __shared__ __align__(16) _Float16 Bs[64 * 64];

    const int tid = threadIdx.x;
    const int lane = tid & 63;
    const int wid = tid >> 6;
    const int lq = lane & 15;
    const int quad = lane >> 4;

    const int rowbase = blockIdx.x * 128;
    const int y = blockIdx.y;
    const int mat = y % 3;
    const int h = y / 3;
    const _Float16* Wy = Wth + (size_t)y * 32768;
    const float* bias = (mat == 0 ? bq : (mat == 1 ? bk : bv)) + (size_t)h * DOUT;
    unsigned short* Out = (mat == 0 ? Qb : (mat == 1 ? Kb : Vb));

    f32x4 acc[8];
    #pragma unroll
    for (int i = 0; i < 8; ++i) { acc[i][0] = 0.f; acc[i][1] = 0.f; acc[i][2] = 0.f; acc[i][3] = 0.f; }

    const int b_ = rowbase >> 10;
    const int lb = rowbase & 1023;
    const size_t baseh = ((size_t)b_ * NH + h);

    if (mat == 2) {
        qkv_core<true>(Xh, Wy, As, Bs, acc, rowbase);
        // acc[mt*4+nt]: l = lb + wid*32 + mt*16 + quad*4 + r (consec), d = nt*16+lq
        #pragma unroll
        for (int nt = 0; nt < 4; ++nt) {
            const int d = nt * 16 + lq;
            const float bz = bias[d];
            #pragma unroll
            for (int mt = 0; mt < 2; ++mt) {
                short4v s;
                #pragma unroll
                for (int r = 0; r < 4; ++r) s[r] = (short)pk1(acc[mt * 4 + nt][r] + bz);
                *reinterpret_cast<short4v*>(
                    &Out[(baseh * DOUT + d) * LL + lb + wid * 32 + mt * 16 + quad * 4]) = s;
            }
        }
    } else {
        qkv_core<false>(Xh, Wy, As, Bs, acc, rowbase);
        // acc[mt*4+nt]: d = nt*16 + quad*4 + r (consec), l = lb + wid*32 + mt*16 + lq
        #pragma unroll
        for (int nt = 0; nt < 4; ++nt) {
            const float4 bz = *reinterpret_cast<const float4*>(&bias[nt * 16 + quad * 4]);
            const float bzv[4] = {bz.x, bz.y, bz.z, bz.w};
            #pragma unroll
            for (int mt = 0; mt < 2; ++mt) {
                const int l = lb + wid * 32 + mt * 16 + lq;
                short4v s;
                #pragma unroll
                for (int r = 0; r < 4; ++r) s[r] = (short)pk1(acc[mt * 4 + nt][r] + bzv[r]);
                *reinterpret_cast<short4v*>(
                    &Out[(baseh * LL + l) * DOUT + nt * 16 + quad * 4]) = s;
            }
        }
    }
}

// ---------------------------------------------------------------------------
// Kernel 2: V suffix sums. Vsuf[b][h][d] = sum_{l>=len} V[b][h][d][l].
// ---------------------------------------------------------------------------
__global__ __launch_bounds__(64) void vsuf_kernel(
    const unsigned short* __restrict__ Vb, const int* __restrict__ traj_len,
    float* __restrict__ Vsuf)
{
    const int bh = blockIdx.x;       // [0, 256)
    const int b = bh >> 3;
    const int d = threadIdx.x;       // [0, 64)
    int len = traj_len[b];
    if (len < 0) len = 0;
    if (len > LL) len = LL;

    const unsigned short* src = Vb + ((size_t)bh * DOUT + d) * LL;
    float s = 0.f;
    int l = len;
    for (; l < LL && (l & 7); ++l) s += bf2f(src[l]);
    for (; l < LL; l += 8) {
        const short8 v = *reinterpret_cast<const short8*>(&src[l]);
        #pragma unroll
        for (int i = 0; i < 8; ++i) s += bf2f((unsigned short)v[i]);
    }
    Vsuf[bh * DOUT + d] = s;
}

// ---------------------------------------------------------------------------
// Kernel 3: bf16-MFMA flash attention, multiplicative mask, max-free softmax.
// Only iterates K-tiles with k < len; the k >= len region contributes p=1
// exactly (exp(0)), folded in analytically via Vsuf and (1024-len).
// ---------------------------------------------------------------------------
__global__ __launch_bounds__(256, 3) void attn_kernel(
    const unsigned short* __restrict__ Qb,
    const unsigned short* __restrict__ Kb,
    const unsigned short* __restrict__ Vb,
    const float* __restrict__ Vsuf,
    const int* __restrict__ traj_len,
    unsigned short* __restrict__ Ob)
{
    __shared__ __align__(16) short lds[16384];   // 32 KB
    short* Ks = lds;              // [64 keys][64 d], swizzled
    short* Vt = lds + 4096;       // [64 d][64 keys], swizzled

    const int tid = threadIdx.x;
    const int lane = tid & 63;
    const int wid = tid >> 6;
    const int lq = lane & 15;
    const int quad = lane >> 4;
    short* Ps = lds + 8192 + wid * 2048;   // per-wave [32 q][64 k], swizzled

    const int qt = blockIdx.x;
    const int h = blockIdx.y;
    const int b = blockIdx.z;

    int len = traj_len[b];
    if (len < 0) len = 0;
    if (len > LL) len = LL;

    const size_t base = ((size_t)b * NH + h) * LL * DOUT;   // same for [l][d] and [d][L]
    const int qbase = qt * 128 + wid * 32;

    // Q fragments (bf16 direct): row = qbase+16g+lq, d = kf*32 + quad*8 .. +7
    short8 qf[2][2];
    #pragma unroll
    for (int g = 0; g < 2; ++g)
        #pragma unroll
        for (int kf = 0; kf < 2; ++kf)
            qf[g][kf] = *reinterpret_cast<const short8*>(
                &Qb[base + (size_t)(qbase + 16 * g + lq) * DOUT + kf * 32 + quad * 8]);

    const float SC = 0.04419417382415922f;   // 1/sqrt(512)
    float Mq[2];
    Mq[0] = ((qbase + lq) < len) ? SC : 0.0f;
    Mq[1] = ((qbase + 16 + lq) < len) ? SC : 0.0f;
    const int krel = len - 4 * quad;         // in-tile k valid iff kt+16nt+r < krel

    f32x4 o[2][4];
    #pragma unroll
    for (int g = 0; g < 2; ++g)
        #pragma unroll
        for (int nt = 0; nt < 4; ++nt) {
            o[g][nt][0] = 0.f; o[g][nt][1] = 0.f; o[g][nt][2] = 0.f; o[g][nt][3] = 0.f;
        }
    float l_acc[2] = {0.0f, 0.0f};

    const int kend = ((len + 63) >> 6) << 6;   // only tiles containing k < len

    for (int kt = 0; kt < kend; kt += 64) {
        __syncthreads();
        // stage K (natural rows) and V (pre-transposed rows), both coalesced b128
        #pragma unroll
        for (int p = 0; p < 2; ++p) {
            const int bidx = tid + p * 256;
            const int m = bidx >> 3, j = bidx & 7;
            const short8 tk = *reinterpret_cast<const short8*>(
                &Kb[base + (size_t)(kt + m) * DOUT + 8 * j]);
            *reinterpret_cast<short8*>(&Ks[m * 64 + 8 * (j ^ (m & 7))]) = tk;
            const short8 tv = *reinterpret_cast<const short8*>(
                &Vb[base + (size_t)m * LL + kt + 8 * j]);
            *reinterpret_cast<short8*>(&Vt[m * 64 + 8 * (j ^ (m & 7))]) = tv;
        }
        __syncthreads();

        // S^T = K . Q^T
        f32x4 sS[2][4];
        #pragma unroll
        for (int nt = 0; nt < 4; ++nt) {
            const int krow = (16 * nt + lq) * 64;
            const short8 k0 = *reinterpret_cast<const short8*>(&Ks[krow + 8 * ((0 + quad) ^ (lq & 7))]);
            const short8 k1 = *reinterpret_cast<const short8*>(&Ks[krow + 8 * ((4 + quad) ^ (lq & 7))]);
            #pragma unroll
            for (int g = 0; g < 2; ++g) {
                f32x4 z;
                z[0] = 0.f; z[1] = 0.f; z[2] = 0.f; z[3] = 0.f;
                z = __builtin_amdgcn_mfma_f32_16x16x32_bf16(k0, qf[g][0], z, 0, 0, 0);
                z = __builtin_amdgcn_mfma_f32_16x16x32_bf16(k1, qf[g][1], z, 0, 0, 0);
                sS[g][nt] = z;
            }
        }

        // p = exp(s*scale*maskq) for k<len, 0 for k>=len (suffix handles those)
        #pragma unroll
        for (int g = 0; g < 2; ++g) {
            #pragma unroll
            for (int nt = 0; nt < 4; ++nt) {
                float pv[4];
                #pragma unroll
                for (int r = 0; r < 4; ++r) {
                    const bool kv = (kt + 16 * nt + r) < krel;
                    pv[r] = kv ? __expf(sS[g][nt][r] * Mq[g]) : 0.0f;
                    l_acc[g] += pv[r];
                }
                int2 w;
                w.x = (int)pk2(pv[0], pv[1]);
                w.y = (int)pk2(pv[2], pv[3]);
                *reinterpret_cast<int2*>(
                    &Ps[(16 * g + lq) * 64 + 8 * ((2 * nt + (quad >> 1)) ^ (lq & 7)) + 4 * (quad & 1)]) = w;
            }
        }

        // O += P . V
        short8 pf[2][2];
        #pragma unroll
        for (int g = 0; g < 2; ++g)
            #pragma unroll
            for (int kf = 0; kf < 2; ++kf)
                pf[g][kf] = *reinterpret_cast<const short8*>(
                    &Ps[(16 * g + lq) * 64 + 8 * ((4 * kf + quad) ^ (lq & 7))]);

        #pragma unroll
        for (int nt = 0; nt < 4; ++nt) {
            const int vrow = (16 * nt + lq) * 64;
            const short8 v0 = *reinterpret_cast<const short8*>(&Vt[vrow + 8 * ((0 + quad) ^ (lq & 7))]);
            const short8 v1 = *reinterpret_cast<const short8*>(&Vt[vrow + 8 * ((4 + quad) ^ (lq & 7))]);
            #pragma unroll
            for (int g = 0; g < 2; ++g) {
                o[g][nt] = __builtin_amdgcn_mfma_f32_16x16x32_bf16(pf[g][0], v0, o[g][nt], 0, 0, 0);
                o[g][nt] = __builtin_amdgcn_mfma_f32_16x16x32_bf16(pf[g][1], v1, o[g][nt], 0, 0, 0);
            }
        }
    }

    // epilogue: suffix contribution + denominator, then store bf16 concat layout
    const float lext = (float)(LL - len);
    float inv[2];
    #pragma unroll
    for (int g = 0; g < 2; ++g) {
        float t = l_acc[g];
        t += __shfl_xor(t, 16);
        t += __shfl_xor(t, 32);
        inv[g] = 1.0f / (t + lext);
    }
    float iq[2][4];
    #pragma unroll
    for (int g = 0; g < 2; ++g)
        #pragma unroll
        for (int r = 0; r < 4; ++r)
            iq[g][r] = __shfl(inv[g], 4 * quad + r, 64);

    const float* vsufp = &Vsuf[((size_t)b * NH + h) * DOUT];
    #pragma unroll
    for (int g = 0; g < 2; ++g) {
        #pragma unroll
        for (int nt = 0; nt < 4; ++nt) {
            const float vs = vsufp[16 * nt + lq];
            #pragma unroll
            for (int r = 0; r < 4; ++r) {
                const int qrow = qbase + 16 * g + 4 * quad + r;
                const float val = (o[g][nt][r] + vs) * iq[g][r];
                Ob[((size_t)b * LL + qrow) * 512 + h * 64 + 16 * nt + lq] = pk1(val);
            }
        }
    }
}

// ---------------------------------------------------------------------------
// Kernel 4: output projection with bf16 MFMA. out[32768,64] = Ob[32768,512] @ Wo.
// Same structure as qkv QK-mode; fp32 float4 stores.
// ---------------------------------------------------------------------------
__global__ __launch_bounds__(256) void outproj_mfma(
    const unsigned short* __restrict__ Ob,
    const unsigned short* __restrict__ Wotb,
    float* __restrict__ out)
{
    __shared__ __align__(16) short As[128 * 64];
    __shared__ __align__(16) short Bs[64 * 64];

    const int tid = threadIdx.x;
    const int lane = tid & 63;
    const int wid = tid >> 6;
    const int lq = lane & 15;
    const int quad = lane >> 4;
    const int rowbase = blockIdx.x * 128;

    f32x4 acc[8];
    #pragma unroll
    for (int i = 0; i < 8; ++i) { acc[i][0] = 0.f; acc[i][1] = 0.f; acc[i][2] = 0.f; acc[i][3] = 0.f; }

    for (int kb = 0; kb < 512; kb += 64) {
        __syncthreads();
        #pragma unroll
        for (int p = 0; p < 4; ++p) {
            const int bidx = tid + p * 256;
            const int m = bidx >> 3, j = bidx & 7;
            const short8 t = *reinterpret_cast<const short8*>(
                &Ob[(size_t)(rowbase + m) * 512 + kb + 8 * j]);
            *reinterpret_cast<short8*>(&As[m * 64 + 8 * (j ^ (m & 7))]) = t;
        }
        #pragma unroll
        for (int p = 0; p < 2; ++p) {
            const int bidx = tid + p * 256;
            const int n = bidx >> 3, j = bidx & 7;
            const short8 t = *reinterpret_cast<const short8*>(
                &Wotb[(size_t)n * 512 + kb + 8 * j]);
            *reinterpret_cast<short8*>(&Bs[n * 64 + 8 * (j ^ (n & 7))]) = t;
        }
        __syncthreads();

        short8 xf[2][2], wf[4][2];
        #pragma unroll
        for (int mt = 0; mt < 2; ++mt)
            #pragma unroll
            for (int kf = 0; kf < 2; ++kf) {
                const int row = wid * 32 + mt * 16 + lq;
                xf[mt][kf] = *reinterpret_cast<const short8*>(
                    &As[row * 64 + 8 * ((4 * kf + quad) ^ (row & 7))]);
            }
        #pragma unroll
        for (int nt = 0; nt < 4; ++nt)
            #pragma unroll
            for (int kf = 0; kf < 2; ++kf)
                wf[nt][kf] = *reinterpret_cast<const short8*>(
                    &Bs[(nt * 16 + lq) * 64 + 8 * ((4 * kf + quad) ^ (lq & 7))]);

        #pragma unroll
        for (int mt = 0; mt < 2; ++mt)
            #pragma unroll
            for (int nt = 0; nt < 4; ++nt)
                #pragma unroll
                for (int kf = 0; kf < 2; ++kf)
                    acc[mt * 4 + nt] = __builtin_amdgcn_mfma_f32_16x16x32_bf16(
                        wf[nt][kf], xf[mt][kf], acc[mt * 4 + nt], 0, 0, 0);
    }

    // acc[mt*4+nt]: d = nt*16 + quad*4 + r (consec), row = rowbase + wid*32 + mt*16 + lq
    #pragma unroll
    for (int nt = 0; nt < 4; ++nt)
        #pragma unroll
        for (int mt = 0; mt < 2; ++mt) {
            const int row = rowbase + wid * 32 + mt * 16 + lq;
            float4 ov;
            ov.x = acc[mt * 4 + nt][0];
            ov.y = acc[mt * 4 + nt][1];
            ov.z = acc[mt * 4 + nt][2];
            ov.w = acc[mt * 4 + nt][3];
            *reinterpret_cast<float4*>(&out[(size_t)row * DOUT + nt * 16 + quad * 4]) = ov;
        }
}

// ---------------------------------------------------------------------------
extern "C" void kernel_launch(void* const* d_in, const int* in_sizes, int n_in,
                              void* d_out, int out_size, void* d_ws, size_t ws_size,
                              hipStream_t stream) {
    const float* joint = (const float*)d_in[0];
    // d_in[1] = delta: dead input (only defines mask shape); never read.
    const int* traj = (const int*)d_in[2];
    const float* Wq = (const float*)d_in[3];
    const float* Wk = (const float*)d_in[4];
    const float* Wv = (const float*)d_in[5];
    const float* bq = (const float*)d_in[6];
    const float* bk = (const float*)d_in[7];
    const float* bv = (const float*)d_in[8];
    const float* Wo = (const float*)d_in[9];
    float* out = (float*)d_out;

    char* ws = (char*)d_ws;
    _Float16* Xh          = (_Float16*)(ws);                    // 33,554,432 B
    _Float16* Wth         = (_Float16*)(ws + 33554432);         //  1,572,864 B
    unsigned short* Wotb  = (unsigned short*)(ws + 35127296);   //     65,536 B
    unsigned short* Qb    = (unsigned short*)(ws + 35192832);   // 33,554,432 B
    unsigned short* Kb    = (unsigned short*)(ws + 68747264);   // 33,554,432 B
    unsigned short* Vb    = (unsigned short*)(ws + 102301696);  // 33,554,432 B
    unsigned short* Ob    = (unsigned short*)(ws + 135856128);  // 33,554,432 B
    float* Vsuf           = (float*)(ws + 169410560);           //     65,536 B

    convert_kernel<<<8592, 256, 0, stream>>>(joint, Wq, Wk, Wv, Wo, Xh, Wth, Wotb);
    qkv_mfma<<<dim3(256, 24), 256, 0, stream>>>(Xh, Wth, bq, bk, bv, Qb, Kb, Vb);
    vsuf_kernel<<<256, 64, 0, stream>>>(Vb, traj, Vsuf);
    attn_kernel<<<dim3(8, NH, BB), 256, 0, stream>>>(Qb, Kb, Vb, Vsuf, traj, Ob);
    outproj_mfma<<<256, 256, 0, stream>>>(Ob, Wotb, out);
}